// Round 6
// baseline (145.356 us; speedup 1.0000x reference)
//
#include <hip/hip_runtime.h>
#include <hip/hip_bf16.h>

#define B_DIM 256
#define NTOK (256 * 512)
#define W1_LD 517
#define TPB 32    // tokens per tile
#define TILES 4   // tiles per block (grid = NTOK/(TPB*TILES) = 1024)

// workspace float offsets
#define WS_DIT 0
#define WS_E 256             // holds 2*e
#define WS_C0 512
#define WS_WX4A 576          // [128] float4 {w512,w513,w514,w515}
#define WS_WX4B 1088         // [128] float4 {w516,b1,w2,0}
#define WS_W1F 2048          // bf16 frag-ordered [8 nblk][16 ks][64 lane][8]
#define WS_SCORE 34816       // [NTOK]

typedef __attribute__((ext_vector_type(8))) short bf16x8;
typedef __attribute__((ext_vector_type(4))) float f32x4;

__device__ __forceinline__ unsigned pk2(float a, float b) {
  __hip_bfloat162 h = __float22bfloat162_rn(make_float2(a, b));
  unsigned r;
  __builtin_memcpy(&r, &h, 4);
  return r;
}

// DPP cross-lane add (VALU pipe)
template <int CTRL>
__device__ __forceinline__ float dpp_add(float v) {
  int s = __builtin_amdgcn_update_dpp(0, __float_as_int(v), CTRL, 0xf, 0xf,
                                      true);
  return v + __int_as_float(s);
}
// sum over each group of 16 consecutive lanes
__device__ __forceinline__ float row16_sum(float v) {
  v = dpp_add<0xB1>(v);   // quad_perm xor1
  v = dpp_add<0x4E>(v);   // quad_perm xor2
  v = dpp_add<0x124>(v);  // row_ror:4
  v = dpp_add<0x128>(v);  // row_ror:8
  return v;
}

__device__ __forceinline__ float wave_sum(float v) {
#pragma unroll
  for (int off = 32; off > 0; off >>= 1) v += __shfl_xor(v, off, 64);
  return v;
}
__device__ __forceinline__ float wave_max(float v) {
#pragma unroll
  for (int off = 32; off > 0; off >>= 1) v = fmaxf(v, __shfl_xor(v, off, 64));
  return v;
}
__device__ __forceinline__ float block_sum(float v, float* scr) {
  v = wave_sum(v);
  int wid = threadIdx.x >> 6;
  __syncthreads();
  if ((threadIdx.x & 63) == 0) scr[wid] = v;
  __syncthreads();
  return scr[0] + scr[1] + scr[2] + scr[3];
}
__device__ __forceinline__ float block_max(float v, float* scr) {
  v = wave_max(v);
  int wid = threadIdx.x >> 6;
  __syncthreads();
  if ((threadIdx.x & 63) == 0) scr[wid] = v;
  __syncthreads();
  return fmaxf(fmaxf(scr[0], scr[1]), fmaxf(scr[2], scr[3]));
}

// ---------------------------------------------------------------------------
// Setup (grid 128): W1 row h -> frag-ordered bf16 W1F; block 0 also builds
// per-d constants (dit, 2e, C0) and packed wx float4 tables.
// ---------------------------------------------------------------------------
__global__ __launch_bounds__(256) void k_setup(
    const float* __restrict__ W1, const float* __restrict__ b1,
    const float* __restrict__ W2, const float* __restrict__ mu_c,
    const float* __restrict__ log_tau2, const float* __restrict__ log_prior,
    float* __restrict__ wsc) {
  const int tid = threadIdx.x;
  const int h = blockIdx.x;
  ushort* w1f = (ushort*)(wsc + WS_W1F);
  const float* wr = W1 + h * W1_LD;
  const int k = 2 * tid;
  const unsigned pk = pk2(wr[k], wr[k + 1]);
  const int flat = (h >> 4) * 8192 + (k >> 5) * 512 +
                   (((k >> 3) & 3) * 16 + (h & 15)) * 8 + (k & 7);
  *(unsigned*)(w1f + flat) = pk;

  if (blockIdx.x == 0) {
    __shared__ float scr[4];
    float lt0 = log_tau2[tid], lt1 = log_tau2[256 + tid];
    float mc0 = mu_c[tid], mc1 = mu_c[256 + tid];
    float it0 = __expf(-lt0), it1 = __expf(-lt1);
    wsc[WS_DIT + tid] = it1 - it0;
    wsc[WS_E + tid] = 2.0f * (mc1 * it1 - mc0 * it0);
    float g = mc1 * mc1 * it1 - mc0 * mc0 * it0 + (lt1 - lt0);
    float sg = block_sum(g, scr);
    if (tid == 0) wsc[WS_C0] = (log_prior[1] - log_prior[0]) - 0.5f * sg;
    if (tid < 128) {
      const float* w1r = W1 + tid * W1_LD;
      *(float4*)(wsc + WS_WX4A + 4 * tid) =
          make_float4(w1r[512], w1r[513], w1r[514], w1r[515]);
      *(float4*)(wsc + WS_WX4B + 4 * tid) =
          make_float4(w1r[516], b1[tid], W2[tid], 0.0f);
    }
  }
}

// ---------------------------------------------------------------------------
// Token kernel: 4 tiles of 32 tokens per block, 512 threads (8 waves),
// 4 blocks/CU. Tile-pipelined: tile i+1's global loads are issued into
// registers BEFORE tile i's MFMA phase; barriers are raw s_barrier with
// lgkmcnt(0) only (no vmcnt drain) so loads stay in flight across MFMA.
// ---------------------------------------------------------------------------
__global__ __launch_bounds__(512, 8) void k_token(
    const float* __restrict__ mu, const float* __restrict__ logvar,
    const float* __restrict__ minutes, const float* __restrict__ b2,
    const float* __restrict__ wsc, float* __restrict__ out_s,
    float* __restrict__ ws_score, float* __restrict__ araw_out) {
  __shared__ __align__(16) ushort A_l[TPB * 512];  // 32KB, XOR-swizzled
  __shared__ float dit_l[256];
  __shared__ float e_l[256];
  __shared__ __align__(16) float4 ex4_l[TPB];  // {s, minutes, snr1, snr2}
  __shared__ float ex1_l[TPB];                 // {snr3}
  __shared__ float red2[8][TPB];

  const int tid = threadIdx.x;
  const int w = tid >> 6;
  const int l = tid & 63;
  const int blockBase = blockIdx.x * (TILES * TPB);

  if (tid < 256) {
    dit_l[tid] = wsc[WS_DIT + tid];
    e_l[tid] = wsc[WS_E + tid];
  }
  const float C0 = wsc[WS_C0];
  __syncthreads();

  const int trow = tid >> 4;  // this thread's token within tile, 0..31
  const int l16 = tid & 15;   // 16 lanes per token
  const int swz = (trow & 7) << 4;
  char* Ab = (char*)A_l;
  const int m_lane = l & 63 & 15;
  const int g = l >> 4;

  float4 m0, m1, m2, m3, v0, v1, v2, v3;
  size_t goff = (size_t)(blockBase + trow) * 256 + l16 * 8;
#define LOADT(gb)                                                         \
  m0 = *(const float4*)(mu + (gb));                                       \
  m1 = *(const float4*)(mu + (gb) + 4);                                   \
  m2 = *(const float4*)(mu + (gb) + 128);                                 \
  m3 = *(const float4*)(mu + (gb) + 132);                                 \
  v0 = *(const float4*)(logvar + (gb));                                   \
  v1 = *(const float4*)(logvar + (gb) + 4);                               \
  v2 = *(const float4*)(logvar + (gb) + 128);                             \
  v3 = *(const float4*)(logvar + (gb) + 132);
  LOADT(goff);

  for (int it = 0; it < TILES; ++it) {
    const int tokbase = blockBase + it * TPB;
    // ---- stats + pack from prefetched regs ----
    float Ss = 0.f, Sm = 0.f, Sl = 0.f, Sc = 0.f;
#define CHUNK(m, lv, dt, ee)                                              \
  {                                                                       \
    const float va = __expf(lv.x), vb = __expf(lv.y), vc = __expf(lv.z),  \
                vd = __expf(lv.w);                                        \
    const float qa = m.x * m.x, qb = m.y * m.y, qc = m.z * m.z,           \
                qd = m.w * m.w;                                           \
    Ss += (va + qa) * dt.x - m.x * ee.x + (vb + qb) * dt.y - m.y * ee.y + \
          (vc + qc) * dt.z - m.z * ee.z + (vd + qd) * dt.w - m.w * ee.w;  \
    Sm += qa + qb + qc + qd;                                              \
    Sl += lv.x + lv.y + lv.z + lv.w;                                      \
    Sc += __fdividef(qa, fmaxf(va, 1e-6f)) +                              \
          __fdividef(qb, fmaxf(vb, 1e-6f)) +                              \
          __fdividef(qc, fmaxf(vc, 1e-6f)) +                              \
          __fdividef(qd, fmaxf(vd, 1e-6f));                               \
  }
    {
      const float4 dA = *(const float4*)&dit_l[l16 * 8];
      const float4 dB = *(const float4*)&dit_l[l16 * 8 + 4];
      const float4 eA = *(const float4*)&e_l[l16 * 8];
      const float4 eB = *(const float4*)&e_l[l16 * 8 + 4];
      CHUNK(m0, v0, dA, eA);
      CHUNK(m1, v1, dB, eB);
      uint4 um, uv;
      um.x = pk2(m0.x, m0.y); um.y = pk2(m0.z, m0.w);
      um.z = pk2(m1.x, m1.y); um.w = pk2(m1.z, m1.w);
      uv.x = pk2(v0.x, v0.y); uv.y = pk2(v0.z, v0.w);
      uv.z = pk2(v1.x, v1.y); uv.w = pk2(v1.z, v1.w);
      const int off = trow * 1024 + l16 * 16;
      *(uint4*)(Ab + (off ^ swz)) = um;
      *(uint4*)(Ab + ((off + 512) ^ swz)) = uv;
    }
    {
      const float4 dA = *(const float4*)&dit_l[128 + l16 * 8];
      const float4 dB = *(const float4*)&dit_l[128 + l16 * 8 + 4];
      const float4 eA = *(const float4*)&e_l[128 + l16 * 8];
      const float4 eB = *(const float4*)&e_l[128 + l16 * 8 + 4];
      CHUNK(m2, v2, dA, eA);
      CHUNK(m3, v3, dB, eB);
      uint4 um, uv;
      um.x = pk2(m2.x, m2.y); um.y = pk2(m2.z, m2.w);
      um.z = pk2(m3.x, m3.y); um.w = pk2(m3.z, m3.w);
      uv.x = pk2(v2.x, v2.y); uv.y = pk2(v2.z, v2.w);
      uv.z = pk2(v3.x, v3.y); uv.w = pk2(v3.z, v3.w);
      const int off = trow * 1024 + 256 + l16 * 16;
      *(uint4*)(Ab + (off ^ swz)) = um;
      *(uint4*)(Ab + ((off + 512) ^ swz)) = uv;
    }
#undef CHUNK
    Ss = row16_sum(Ss);
    Sm = row16_sum(Sm);
    Sl = row16_sum(Sl);
    Sc = row16_sum(Sc);
    if (l16 == 0) {
      const float sval = -0.5f * Ss + C0;
      const float mn = minutes[tokbase + trow];
      ex4_l[trow] = make_float4(sval, mn, sqrtf(Sm) * (1.0f / 16.0f),
                                Sl * (1.0f / 256.0f));
      ex1_l[trow] = Sc * (1.0f / 256.0f);
      out_s[tokbase + trow] = sval;
      ws_score[tokbase + trow] = Sc;
    }
    // ---- issue next tile's loads (stay in flight across MFMA) ----
    if (it + 1 < TILES) {
      goff += TPB * 256;
      LOADT(goff);
    }
    // A-ready barrier: LDS visibility only, NO vmcnt drain
    asm volatile("s_waitcnt lgkmcnt(0)" ::: "memory");
    __builtin_amdgcn_s_barrier();

    // ---- MFMA GEMM h = X * W1^T (wave w owns h in [16w,16w+16)) ----
    f32x4 acc0 = {0.f, 0.f, 0.f, 0.f};
    f32x4 acc1 = {0.f, 0.f, 0.f, 0.f};
    const int swzA = (m_lane & 7) << 4;
    const int rowA0 = m_lane * 1024;
    const int rowA1 = rowA0 + 16 * 1024;
    const ushort* bp = (const ushort*)(wsc + WS_W1F) + w * 8192 + l * 8;
#pragma unroll 4
    for (int ks = 0; ks < 16; ++ks) {
      const int kByte = ks * 64 + (l >> 4) * 16;
      bf16x8 a0 = *(const bf16x8*)(Ab + ((rowA0 + kByte) ^ swzA));
      bf16x8 a1 = *(const bf16x8*)(Ab + ((rowA1 + kByte) ^ swzA));
      bf16x8 bq = *(const bf16x8*)(bp + ks * 512);
      acc0 = __builtin_amdgcn_mfma_f32_16x16x32_bf16(a0, bq, acc0, 0, 0, 0);
      acc1 = __builtin_amdgcn_mfma_f32_16x16x32_bf16(a1, bq, acc1, 0, 0, 0);
    }

    // ---- epilogue: extras + relu + W2 dot; DPP reduce over 16 h-lanes ----
    {
      const int h0 = 16 * w + m_lane;
      const float4 wa = *(const float4*)(wsc + WS_WX4A + 4 * h0);
      const float4 wb = *(const float4*)(wsc + WS_WX4B + 4 * h0);
#pragma unroll
      for (int mf = 0; mf < 2; ++mf) {
        const f32x4 aN = mf ? acc1 : acc0;
#pragma unroll
        for (int r = 0; r < 4; ++r) {
          const int t_loc = 16 * mf + 4 * g + r;
          const float4 e4 = ex4_l[t_loc];
          float hp = aN[r] + e4.x * wa.x + e4.y * wa.y + e4.z * wa.z +
                     e4.w * wa.w + ex1_l[t_loc] * wb.x + wb.y;
          float cs = fmaxf(hp, 0.f) * wb.z;
          cs = row16_sum(cs);
          if (m_lane == 0) red2[w][t_loc] = cs;
        }
      }
    }
    // red2-ready barrier (also fences tile's A/ex reads before next pack)
    asm volatile("s_waitcnt lgkmcnt(0)" ::: "memory");
    __builtin_amdgcn_s_barrier();
    if (tid < TPB) {
      float z = red2[0][tid] + red2[1][tid] + red2[2][tid] + red2[3][tid] +
                red2[4][tid] + red2[5][tid] + red2[6][tid] + red2[7][tid] +
                b2[0];
      araw_out[tokbase + tid] = 1.0f / (1.0f + __expf(-z));
    }
  }
#undef LOADT
}

// ---------------------------------------------------------------------------
// Per-batch-row kernel: 256 blocks, 256 threads x 2 tokens.
// a_io holds a_raw on entry (written by k_token), final a on exit.
// ---------------------------------------------------------------------------
__global__ __launch_bounds__(256) void k_row(
    const float* __restrict__ minutes, const float* __restrict__ s_in,
    const float* __restrict__ score_in, float* a_io,
    const float* __restrict__ alpha_logits,
    const float* __restrict__ attn_lambda_logit,
    const float* __restrict__ decay_rate_log, float* __restrict__ out_total) {
  __shared__ float scr[4];
  int row = blockIdx.x;
  int tid = threadIdx.x;
  int base = row * 512;
  float sc0 = score_in[base + tid], sc1 = score_in[base + 256 + tid];
  float sv0 = s_in[base + tid], sv1 = s_in[base + 256 + tid];
  float ar0 = a_io[base + tid], ar1 = a_io[base + 256 + tid];
  float mn0 = minutes[base + tid], mn1 = minutes[base + 256 + tid];

  float msc = block_max(fmaxf(sc0, sc1), scr);
  float mmn = block_max(fmaxf(mn0, mn1), scr);
  float sar = block_sum(ar0 + ar1, scr);
  float e0 = __expf(sc0 - msc), e1 = __expf(sc1 - msc);
  float se = block_sum(e0 + e1, scr);

  float lam = 1.0f / (1.0f + __expf(-attn_lambda_logit[0]));
  float alpha = 1.0f / (1.0f + __expf(-alpha_logits[0]));
  float rate = log1pf(__expf(decay_rate_log[0]));

  float inv_sar = 1.0f / fmaxf(sar, 1e-6f);
  float inv_se = 1.0f / se;
  float a00 = lam * ar0 * inv_sar + (1.0f - lam) * e0 * inv_se;
  float a01 = lam * ar1 * inv_sar + (1.0f - lam) * e1 * inv_se;
  float dh0 = fmaxf(mmn - mn0, 0.0f) * (1.0f / 60.0f);
  float dh1 = fmaxf(mmn - mn1, 0.0f) * (1.0f / 60.0f);
  float w0 = a00 * __expf(-rate * dh0);
  float w1 = a01 * __expf(-rate * dh1);
  float sw = block_sum(w0 + w1, scr);
  float inv_sw = 1.0f / fmaxf(sw, 1e-6f);
  float af0 = w0 * inv_sw, af1 = w1 * inv_sw;
  a_io[base + tid] = af0;
  a_io[base + 256 + tid] = af1;
  float smain = block_sum(af0 * sv0 + af1 * sv1, scr);
  float sg0 = 1.0f / (1.0f + __expf(-sv0));
  float sg1 = 1.0f / (1.0f + __expf(-sv1));
  float p0 = fminf(fmaxf(sg0 * af0, 1e-6f), 1.0f - 1e-6f);
  float p1 = fminf(fmaxf(sg1 * af1, 1e-6f), 1.0f - 1e-6f);
  float slg = block_sum(log1pf(-p0) + log1pf(-p1), scr);
  if (tid == 0) {
    float por = 1.0f - __expf(slg);
    por = fminf(fmaxf(por, 1e-6f), 1.0f - 1e-6f);
    float sor = logf(por) - log1pf(-por);
    out_total[row] = alpha * smain + (1.0f - alpha) * sor;
  }
}

extern "C" void kernel_launch(void* const* d_in, const int* in_sizes, int n_in,
                              void* d_out, int out_size, void* d_ws,
                              size_t ws_size, hipStream_t stream) {
  const float* mu = (const float*)d_in[0];
  const float* logvar = (const float*)d_in[1];
  const float* minutes = (const float*)d_in[2];
  const float* mu_c = (const float*)d_in[3];
  const float* log_tau2 = (const float*)d_in[4];
  const float* log_prior = (const float*)d_in[5];
  const float* W1 = (const float*)d_in[6];
  const float* b1 = (const float*)d_in[7];
  const float* W2 = (const float*)d_in[8];
  const float* b2 = (const float*)d_in[9];
  const float* alpha_logits = (const float*)d_in[10];
  const float* attn_lambda_logit = (const float*)d_in[11];
  const float* decay_rate_log = (const float*)d_in[12];

  float* out = (float*)d_out;
  float* out_total = out;             // [256]
  float* out_s = out + B_DIM;        // [131072]
  float* out_a = out + B_DIM + NTOK; // [131072] — holds a_raw between kernels
  float* wsc = (float*)d_ws;
  float* ws_score = wsc + WS_SCORE;

  k_setup<<<128, 256, 0, stream>>>(W1, b1, W2, mu_c, log_tau2, log_prior, wsc);
  k_token<<<NTOK / (TPB * TILES), 512, 0, stream>>>(mu, logvar, minutes, b2,
                                                    wsc, out_s, ws_score,
                                                    out_a);
  k_row<<<B_DIM, 256, 0, stream>>>(minutes, out_s, ws_score, out_a,
                                   alpha_logits, attn_lambda_logit,
                                   decay_rate_log, out_total);
}

// Round 9
// 69.039 us; speedup vs baseline: 2.1054x; 2.1054x over previous
//
#include <hip/hip_runtime.h>
#include <hip/hip_bf16.h>

#define B_DIM 256
#define NTOK (256 * 512)
#define W1_LD 517
#define TPB 32  // tokens per k_token block

// workspace float offsets
#define WS_DIT 0
#define WS_E 256             // holds 2*e
#define WS_C0 512
#define WS_W1F 1024          // bf16 frag-ordered [8 nblk][17 ks][64 lane][8]
                             // = 69632 ushorts = 34816 floats -> [1024,35840)
#define WS_SCORE 36864       // [NTOK]  (must be >= 35840)

typedef __attribute__((ext_vector_type(8))) short bf16x8;
typedef __attribute__((ext_vector_type(4))) float f32x4;

__device__ __forceinline__ unsigned pk2(float a, float b) {
  __hip_bfloat162 h = __float22bfloat162_rn(make_float2(a, b));
  unsigned r;
  __builtin_memcpy(&r, &h, 4);
  return r;
}

// DPP cross-lane add (VALU pipe)
template <int CTRL>
__device__ __forceinline__ float dpp_add(float v) {
  int s = __builtin_amdgcn_update_dpp(0, __float_as_int(v), CTRL, 0xf, 0xf,
                                      true);
  return v + __int_as_float(s);
}
// sum over each group of 8 consecutive lanes (valid at lanes with (l&7)==0).
// Steps: quad butterflies (xor1, xor2) -> every quad holds its quad-sum;
// then row_half_mirror (0x141, j <-> 7-j within each 8-lane half) pairs
// quad a with quad b DIRECTION-UNAMBIGUOUSLY. (R8 bug: row_ror:4 is a
// 16-lane rotation whose direction mixes the two tokens sharing a row.)
__device__ __forceinline__ float row8_sum(float v) {
  v = dpp_add<0xB1>(v);   // quad_perm xor1
  v = dpp_add<0x4E>(v);   // quad_perm xor2
  v = dpp_add<0x141>(v);  // row_half_mirror: quad a <-> quad b within 8
  return v;
}
// sum over each group of 16 consecutive lanes (rotation direction
// irrelevant for the full-row sum — verified R5/R6 passing)
__device__ __forceinline__ float row16_sum(float v) {
  v = dpp_add<0xB1>(v);
  v = dpp_add<0x4E>(v);
  v = dpp_add<0x124>(v);  // row_ror:4
  v = dpp_add<0x128>(v);  // row_ror:8
  return v;
}

__device__ __forceinline__ float wave_sum(float v) {
#pragma unroll
  for (int off = 32; off > 0; off >>= 1) v += __shfl_xor(v, off, 64);
  return v;
}
__device__ __forceinline__ float wave_max(float v) {
#pragma unroll
  for (int off = 32; off > 0; off >>= 1) v = fmaxf(v, __shfl_xor(v, off, 64));
  return v;
}
__device__ __forceinline__ float block_sum(float v, float* scr) {
  v = wave_sum(v);
  int wid = threadIdx.x >> 6;
  __syncthreads();
  if ((threadIdx.x & 63) == 0) scr[wid] = v;
  __syncthreads();
  return scr[0] + scr[1] + scr[2] + scr[3];
}

// ---------------------------------------------------------------------------
// Setup (grid 128): W1 row h -> frag-ordered bf16 W1F with 17 K-steps:
// steps 0..15 = W1[:,0:512]; step 16 = {w512..w516, b1, 0...} (extras+bias).
// Block 0 also builds per-d constants (dit, 2e, C0).
// ---------------------------------------------------------------------------
__global__ __launch_bounds__(256) void k_setup(
    const float* __restrict__ W1, const float* __restrict__ b1,
    const float* __restrict__ mu_c, const float* __restrict__ log_tau2,
    const float* __restrict__ log_prior, float* __restrict__ wsc) {
  const int tid = threadIdx.x;
  const int h = blockIdx.x;
  ushort* w1f = (ushort*)(wsc + WS_W1F);
  const float* wr = W1 + h * W1_LD;
  const int k = 2 * tid;
  const unsigned pk = pk2(wr[k], wr[k + 1]);
  const int flat = (h >> 4) * 8704 + (k >> 5) * 512 +
                   (((k >> 3) & 3) * 16 + (h & 15)) * 8 + (k & 7);
  *(unsigned*)(w1f + flat) = pk;
  if (tid == 0) {
    const int base16 = (h >> 4) * 8704 + 16 * 512;
    uint4 g0;
    g0.x = pk2(wr[512], wr[513]);
    g0.y = pk2(wr[514], wr[515]);
    g0.z = pk2(wr[516], b1[h]);
    g0.w = 0u;
    *(uint4*)(w1f + base16 + ((h & 15)) * 8) = g0;
    const uint4 z = {0u, 0u, 0u, 0u};
    *(uint4*)(w1f + base16 + (16 + (h & 15)) * 8) = z;
    *(uint4*)(w1f + base16 + (32 + (h & 15)) * 8) = z;
    *(uint4*)(w1f + base16 + (48 + (h & 15)) * 8) = z;
  }

  if (blockIdx.x == 0) {
    __shared__ float scr[4];
    float lt0 = log_tau2[tid], lt1 = log_tau2[256 + tid];
    float mc0 = mu_c[tid], mc1 = mu_c[256 + tid];
    float it0 = __expf(-lt0), it1 = __expf(-lt1);
    wsc[WS_DIT + tid] = it1 - it0;
    wsc[WS_E + tid] = 2.0f * (mc1 * it1 - mc0 * it0);
    float g = mc1 * mc1 * it1 - mc0 * mc0 * it0 + (lt1 - lt0);
    float sg = block_sum(g, scr);
    if (tid == 0) wsc[WS_C0] = (log_prior[1] - log_prior[0]) - 0.5f * sg;
  }
}

// ---------------------------------------------------------------------------
// Token kernel: 32 tokens/block, 256 threads (4 waves), 4 blocks/CU.
// Phase 1: 8 lanes/token x 4 iters (8 d each); stats in regs, DPP row8
//          reduce; bf16 A-tile b128-written to XOR-swizzled LDS; extras row
//          (s, minutes, snr1..3, 1) written bf16 to axl.
// Phase 2: MFMA 16x16x32_bf16, 17 K-steps (16 main + 1 extras+bias);
//          per-wave N=32 (2 frags), M=32 (2 frags).
// Epilogue: relu(acc)*W2, DPP row16 reduce, cross-wave via red2.
// ---------------------------------------------------------------------------
__global__ __launch_bounds__(256, 4) void k_token(
    const float* __restrict__ mu, const float* __restrict__ logvar,
    const float* __restrict__ minutes, const float* __restrict__ W2g,
    const float* __restrict__ b2, const float* __restrict__ wsc,
    float* __restrict__ out_s, float* __restrict__ ws_score,
    float* __restrict__ araw_out) {
  __shared__ __align__(16) ushort A_l[TPB * 512];  // 32KB, XOR-swizzled
  __shared__ __align__(16) ushort axl[TPB * 32];   // 2KB extras rows
  __shared__ float red2[4][TPB];

  const int tid = threadIdx.x;
  const int w = tid >> 6;
  const int l = tid & 63;
  const int tokbase = blockIdx.x * TPB;
  const float C0 = wsc[WS_C0];

  // zero axl tails (bytes 16..63 of each 64B row)
  if (tid < 96) {
    const int row = tid & 31;
    const int c = tid >> 5;
    const uint4 z = {0u, 0u, 0u, 0u};
    *(uint4*)((char*)axl + row * 64 + 16 + c * 16) = z;
  }

  // ---- phase 1: stream + in-register stats + bf16 A-tile staging ----
  const int trow = tid >> 3;  // this thread's token, 0..31
  const int l8 = tid & 7;     // 8 lanes per token, 8 d per iter
  const int swz = (trow & 7) << 4;
  char* Ab = (char*)A_l;
  const size_t gbase = (size_t)(tokbase + trow) * 256 + l8 * 8;
  const float* ditg = wsc + WS_DIT + l8 * 8;
  const float* eg = wsc + WS_E + l8 * 8;
  float Ss = 0.f, Sm = 0.f, Sl = 0.f, Sc = 0.f;
#pragma unroll
  for (int t = 0; t < 4; ++t) {
    const float4 m0 = *(const float4*)(mu + gbase + t * 64);
    const float4 m1 = *(const float4*)(mu + gbase + t * 64 + 4);
    const float4 v0 = *(const float4*)(logvar + gbase + t * 64);
    const float4 v1 = *(const float4*)(logvar + gbase + t * 64 + 4);
    const float4 dA = *(const float4*)(ditg + t * 64);
    const float4 dB = *(const float4*)(ditg + t * 64 + 4);
    const float4 eA = *(const float4*)(eg + t * 64);
    const float4 eB = *(const float4*)(eg + t * 64 + 4);
#define CHUNK(m, lv, dt, ee)                                              \
  {                                                                       \
    const float va = __expf(lv.x), vb = __expf(lv.y), vc = __expf(lv.z),  \
                vd = __expf(lv.w);                                        \
    const float na = __expf(-lv.x), nb = __expf(-lv.y),                   \
                nc = __expf(-lv.z), nd = __expf(-lv.w);                   \
    const float qa = m.x * m.x, qb = m.y * m.y, qc = m.z * m.z,           \
                qd = m.w * m.w;                                           \
    Ss += (va + qa) * dt.x - m.x * ee.x + (vb + qb) * dt.y - m.y * ee.y + \
          (vc + qc) * dt.z - m.z * ee.z + (vd + qd) * dt.w - m.w * ee.w;  \
    Sm += qa + qb + qc + qd;                                              \
    Sl += lv.x + lv.y + lv.z + lv.w;                                      \
    Sc += qa * na + qb * nb + qc * nc + qd * nd;                          \
  }
    CHUNK(m0, v0, dA, eA);
    CHUNK(m1, v1, dB, eB);
#undef CHUNK
    uint4 um, uv;
    um.x = pk2(m0.x, m0.y);
    um.y = pk2(m0.z, m0.w);
    um.z = pk2(m1.x, m1.y);
    um.w = pk2(m1.z, m1.w);
    uv.x = pk2(v0.x, v0.y);
    uv.y = pk2(v0.z, v0.w);
    uv.z = pk2(v1.x, v1.y);
    uv.w = pk2(v1.z, v1.w);
    const int off = trow * 1024 + t * 128 + l8 * 16;
    *(uint4*)(Ab + (off ^ swz)) = um;
    *(uint4*)(Ab + ((off + 512) ^ swz)) = uv;
  }
  // reduce across the 8 lanes of this token (valid at l8==0)
  Ss = row8_sum(Ss);
  Sm = row8_sum(Sm);
  Sl = row8_sum(Sl);
  Sc = row8_sum(Sc);
  if (l8 == 0) {
    const float sval = -0.5f * Ss + C0;
    const float mn = minutes[tokbase + trow];
    uint4 ex;
    ex.x = pk2(sval, mn);
    ex.y = pk2(sqrtf(Sm) * (1.0f / 16.0f), Sl * (1.0f / 256.0f));
    ex.z = pk2(Sc * (1.0f / 256.0f), 1.0f);
    ex.w = 0u;
    *(uint4*)((char*)axl + trow * 64) = ex;
    out_s[tokbase + trow] = sval;
    ws_score[tokbase + trow] = Sc;
  }
  __syncthreads();

  // ---- phase 2: MFMA GEMM (17 K-steps; wave w owns h in [32w, 32w+32)) ----
  f32x4 a00 = {0.f, 0.f, 0.f, 0.f};
  f32x4 a01 = {0.f, 0.f, 0.f, 0.f};
  f32x4 a10 = {0.f, 0.f, 0.f, 0.f};
  f32x4 a11 = {0.f, 0.f, 0.f, 0.f};
  const int m_lane = l & 15;
  const int swzA = (m_lane & 7) << 4;
  const int rowA0 = m_lane * 1024;
  const int rowA1 = rowA0 + 16 * 1024;
  const ushort* w1f = (const ushort*)(wsc + WS_W1F);
  const ushort* bp0 = w1f + (2 * w) * 8704 + l * 8;
  const ushort* bp1 = bp0 + 8704;
#pragma unroll 4
  for (int ks = 0; ks < 16; ++ks) {
    const int kByte = ks * 64 + (l >> 4) * 16;
    bf16x8 f0 = *(const bf16x8*)(Ab + ((rowA0 + kByte) ^ swzA));
    bf16x8 f1 = *(const bf16x8*)(Ab + ((rowA1 + kByte) ^ swzA));
    bf16x8 bq0 = *(const bf16x8*)(bp0 + ks * 512);
    bf16x8 bq1 = *(const bf16x8*)(bp1 + ks * 512);
    a00 = __builtin_amdgcn_mfma_f32_16x16x32_bf16(f0, bq0, a00, 0, 0, 0);
    a01 = __builtin_amdgcn_mfma_f32_16x16x32_bf16(f0, bq1, a01, 0, 0, 0);
    a10 = __builtin_amdgcn_mfma_f32_16x16x32_bf16(f1, bq0, a10, 0, 0, 0);
    a11 = __builtin_amdgcn_mfma_f32_16x16x32_bf16(f1, bq1, a11, 0, 0, 0);
  }
  {  // extras + bias step (K-step 16)
    const int xb = (l >> 4) * 16;
    bf16x8 f0 = *(const bf16x8*)((char*)axl + m_lane * 64 + xb);
    bf16x8 f1 = *(const bf16x8*)((char*)axl + (m_lane + 16) * 64 + xb);
    bf16x8 bq0 = *(const bf16x8*)(bp0 + 16 * 512);
    bf16x8 bq1 = *(const bf16x8*)(bp1 + 16 * 512);
    a00 = __builtin_amdgcn_mfma_f32_16x16x32_bf16(f0, bq0, a00, 0, 0, 0);
    a01 = __builtin_amdgcn_mfma_f32_16x16x32_bf16(f0, bq1, a01, 0, 0, 0);
    a10 = __builtin_amdgcn_mfma_f32_16x16x32_bf16(f1, bq0, a10, 0, 0, 0);
    a11 = __builtin_amdgcn_mfma_f32_16x16x32_bf16(f1, bq1, a11, 0, 0, 0);
  }

  // ---- epilogue: relu + W2 dot; DPP reduce over 16 h-lanes ----
  const int g = l >> 4;
  const float w2a = W2g[32 * w + m_lane];
  const float w2b = W2g[32 * w + m_lane + 16];
#pragma unroll
  for (int mf = 0; mf < 2; ++mf) {
    const f32x4 aN0 = mf ? a10 : a00;
    const f32x4 aN1 = mf ? a11 : a01;
#pragma unroll
    for (int r = 0; r < 4; ++r) {
      const int t_loc = 16 * mf + 4 * g + r;
      float cs = fmaxf(aN0[r], 0.f) * w2a + fmaxf(aN1[r], 0.f) * w2b;
      cs = row16_sum(cs);
      if (m_lane == 0) red2[w][t_loc] = cs;
    }
  }
  __syncthreads();
  if (tid < TPB) {
    float z = red2[0][tid] + red2[1][tid] + red2[2][tid] + red2[3][tid] +
              b2[0];
    araw_out[tokbase + tid] = 1.0f / (1.0f + __expf(-z));
  }
}

// ---------------------------------------------------------------------------
// Per-batch-row kernel: 256 blocks, 256 threads x 2 tokens; 4 barriers.
// a_io holds a_raw on entry (written by k_token), final a on exit.
// ---------------------------------------------------------------------------
__global__ __launch_bounds__(256) void k_row(
    const float* __restrict__ minutes, const float* __restrict__ s_in,
    const float* __restrict__ score_in, float* a_io,
    const float* __restrict__ alpha_logits,
    const float* __restrict__ attn_lambda_logit,
    const float* __restrict__ decay_rate_log, float* __restrict__ out_total) {
  __shared__ float scrA[4][4];
  __shared__ float scrB[4];
  __shared__ float scrC[4];
  __shared__ float scrD[4][2];
  const int row = blockIdx.x;
  const int tid = threadIdx.x;
  const int w = tid >> 6;
  const int base = row * 512;
  const float sc0 = score_in[base + tid], sc1 = score_in[base + 256 + tid];
  const float sv0 = s_in[base + tid], sv1 = s_in[base + 256 + tid];
  const float ar0 = a_io[base + tid], ar1 = a_io[base + 256 + tid];
  const float mn0 = minutes[base + tid], mn1 = minutes[base + 256 + tid];

  const float vsc = wave_max(fmaxf(sc0, sc1));
  const float vmn = wave_max(fmaxf(mn0, mn1));
  const float var_ = wave_sum(ar0 + ar1);
  if ((tid & 63) == 0) {
    scrA[w][0] = vsc;
    scrA[w][1] = vmn;
    scrA[w][2] = var_;
  }
  __syncthreads();
  const float msc = fmaxf(fmaxf(scrA[0][0], scrA[1][0]),
                          fmaxf(scrA[2][0], scrA[3][0]));
  const float mmn = fmaxf(fmaxf(scrA[0][1], scrA[1][1]),
                          fmaxf(scrA[2][1], scrA[3][1]));
  const float sar = scrA[0][2] + scrA[1][2] + scrA[2][2] + scrA[3][2];

  const float e0 = __expf(sc0 - msc), e1 = __expf(sc1 - msc);
  const float vse = wave_sum(e0 + e1);
  if ((tid & 63) == 0) scrB[w] = vse;
  __syncthreads();
  const float se = scrB[0] + scrB[1] + scrB[2] + scrB[3];

  const float lam = 1.0f / (1.0f + __expf(-attn_lambda_logit[0]));
  const float alpha = 1.0f / (1.0f + __expf(-alpha_logits[0]));
  const float rate = log1pf(__expf(decay_rate_log[0]));

  const float inv_sar = 1.0f / fmaxf(sar, 1e-6f);
  const float inv_se = 1.0f / se;
  const float a00 = lam * ar0 * inv_sar + (1.0f - lam) * e0 * inv_se;
  const float a01 = lam * ar1 * inv_sar + (1.0f - lam) * e1 * inv_se;
  const float dh0 = fmaxf(mmn - mn0, 0.0f) * (1.0f / 60.0f);
  const float dh1 = fmaxf(mmn - mn1, 0.0f) * (1.0f / 60.0f);
  const float w0 = a00 * __expf(-rate * dh0);
  const float w1 = a01 * __expf(-rate * dh1);
  const float vsw = wave_sum(w0 + w1);
  if ((tid & 63) == 0) scrC[w] = vsw;
  __syncthreads();
  const float sw = scrC[0] + scrC[1] + scrC[2] + scrC[3];
  const float inv_sw = 1.0f / fmaxf(sw, 1e-6f);
  const float af0 = w0 * inv_sw, af1 = w1 * inv_sw;
  a_io[base + tid] = af0;
  a_io[base + 256 + tid] = af1;

  const float sg0 = 1.0f / (1.0f + __expf(-sv0));
  const float sg1 = 1.0f / (1.0f + __expf(-sv1));
  const float p0 = fminf(fmaxf(sg0 * af0, 1e-6f), 1.0f - 1e-6f);
  const float p1 = fminf(fmaxf(sg1 * af1, 1e-6f), 1.0f - 1e-6f);
  const float vsm = wave_sum(af0 * sv0 + af1 * sv1);
  const float vlg = wave_sum(log1pf(-p0) + log1pf(-p1));
  if ((tid & 63) == 0) {
    scrD[w][0] = vsm;
    scrD[w][1] = vlg;
  }
  __syncthreads();
  if (tid == 0) {
    const float smain = scrD[0][0] + scrD[1][0] + scrD[2][0] + scrD[3][0];
    const float slg = scrD[0][1] + scrD[1][1] + scrD[2][1] + scrD[3][1];
    float por = 1.0f - __expf(slg);
    por = fminf(fmaxf(por, 1e-6f), 1.0f - 1e-6f);
    const float sor = logf(por) - log1pf(-por);
    out_total[row] = alpha * smain + (1.0f - alpha) * sor;
  }
}

extern "C" void kernel_launch(void* const* d_in, const int* in_sizes, int n_in,
                              void* d_out, int out_size, void* d_ws,
                              size_t ws_size, hipStream_t stream) {
  const float* mu = (const float*)d_in[0];
  const float* logvar = (const float*)d_in[1];
  const float* minutes = (const float*)d_in[2];
  const float* mu_c = (const float*)d_in[3];
  const float* log_tau2 = (const float*)d_in[4];
  const float* log_prior = (const float*)d_in[5];
  const float* W1 = (const float*)d_in[6];
  const float* b1 = (const float*)d_in[7];
  const float* W2 = (const float*)d_in[8];
  const float* b2 = (const float*)d_in[9];
  const float* alpha_logits = (const float*)d_in[10];
  const float* attn_lambda_logit = (const float*)d_in[11];
  const float* decay_rate_log = (const float*)d_in[12];

  float* out = (float*)d_out;
  float* out_total = out;             // [256]
  float* out_s = out + B_DIM;        // [131072]
  float* out_a = out + B_DIM + NTOK; // [131072] — holds a_raw between kernels
  float* wsc = (float*)d_ws;
  float* ws_score = wsc + WS_SCORE;

  k_setup<<<128, 256, 0, stream>>>(W1, b1, mu_c, log_tau2, log_prior, wsc);
  k_token<<<NTOK / TPB, 256, 0, stream>>>(mu, logvar, minutes, W2, b2, wsc,
                                          out_s, ws_score, out_a);
  k_row<<<B_DIM, 256, 0, stream>>>(minutes, out_s, ws_score, out_a,
                                   alpha_logits, attn_lambda_logit,
                                   decay_rate_log, out_total);
}

// Round 10
// 58.315 us; speedup vs baseline: 2.4926x; 1.1839x over previous
//
#include <hip/hip_runtime.h>
#include <hip/hip_bf16.h>

#define B_DIM 256
#define NTOK (256 * 512)
#define W1_LD 517
#define TPB 32  // tokens per k_token block

// workspace float offsets
#define WS_DIT 0
#define WS_E 256             // holds 2*e
#define WS_C0 512
#define WS_W1F 1024          // fp8 frag-ordered [8 nblk][16 ks][64 lane][8B]
                             // = 65536 B = 16384 floats -> [1024, 17408)
#define WS_W1X 17408         // bf16 extras step [8 nblk][64 lane][8]
                             // = 4096 ushorts = 2048 floats -> [17408, 19456)
#define WS_SCORE 20480       // [NTOK]

typedef __attribute__((ext_vector_type(8))) short bf16x8;
typedef __attribute__((ext_vector_type(4))) float f32x4;
typedef long long i64;

__device__ __forceinline__ unsigned pk2(float a, float b) {
  __hip_bfloat162 h = __float22bfloat162_rn(make_float2(a, b));
  unsigned r;
  __builtin_memcpy(&r, &h, 4);
  return r;
}
// pack 4 floats -> 4 fp8 e4m3 bytes in one u32
__device__ __forceinline__ unsigned pk4f8(float a, float b, float c, float d) {
  int r = __builtin_amdgcn_cvt_pk_fp8_f32(a, b, 0, false);
  r = __builtin_amdgcn_cvt_pk_fp8_f32(c, d, r, true);
  return (unsigned)r;
}

// DPP cross-lane add (VALU pipe)
template <int CTRL>
__device__ __forceinline__ float dpp_add(float v) {
  int s = __builtin_amdgcn_update_dpp(0, __float_as_int(v), CTRL, 0xf, 0xf,
                                      true);
  return v + __int_as_float(s);
}
// sum over each group of 8 consecutive lanes (valid at lanes with (l&7)==0).
// quad butterflies then row_half_mirror (0x141) — direction-unambiguous.
__device__ __forceinline__ float row8_sum(float v) {
  v = dpp_add<0xB1>(v);   // quad_perm xor1
  v = dpp_add<0x4E>(v);   // quad_perm xor2
  v = dpp_add<0x141>(v);  // row_half_mirror
  return v;
}
// sum over each group of 16 consecutive lanes
__device__ __forceinline__ float row16_sum(float v) {
  v = dpp_add<0xB1>(v);
  v = dpp_add<0x4E>(v);
  v = dpp_add<0x124>(v);  // row_ror:4
  v = dpp_add<0x128>(v);  // row_ror:8
  return v;
}

__device__ __forceinline__ float wave_sum(float v) {
#pragma unroll
  for (int off = 32; off > 0; off >>= 1) v += __shfl_xor(v, off, 64);
  return v;
}
__device__ __forceinline__ float wave_max(float v) {
#pragma unroll
  for (int off = 32; off > 0; off >>= 1) v = fmaxf(v, __shfl_xor(v, off, 64));
  return v;
}
__device__ __forceinline__ float block_sum(float v, float* scr) {
  v = wave_sum(v);
  int wid = threadIdx.x >> 6;
  __syncthreads();
  if ((threadIdx.x & 63) == 0) scr[wid] = v;
  __syncthreads();
  return scr[0] + scr[1] + scr[2] + scr[3];
}

// ---------------------------------------------------------------------------
// K-axis reorder: position p in [0,512) maps to source W1 column
//   (p&15)<8 ? (p>>4)*8 + (p&7) : 256 + (p>>4)*8 + (p&7)
// i.e. k-blocks interleave [mu d0..d0+7 | lv d0..d0+7]. The GEMM sum is
// order-invariant; this makes each thread's 8 mu + 8 lv bytes contiguous.
// ---------------------------------------------------------------------------
__global__ __launch_bounds__(256) void k_setup(
    const float* __restrict__ W1, const float* __restrict__ b1,
    const float* __restrict__ mu_c, const float* __restrict__ log_tau2,
    const float* __restrict__ log_prior, float* __restrict__ wsc) {
  const int tid = threadIdx.x;
  const int h = blockIdx.x;
  const float* wr = W1 + h * W1_LD;
  // main fp8 W1F: thread handles positions p, p+1
  {
    const int p = 2 * tid;
    const int c0 = ((p & 15) < 8) ? (p >> 4) * 8 + (p & 7)
                                  : 256 + (p >> 4) * 8 + (p & 7);
    const int p1 = p + 1;
    const int c1 = ((p1 & 15) < 8) ? (p1 >> 4) * 8 + (p1 & 7)
                                   : 256 + (p1 >> 4) * 8 + (p1 & 7);
    const int pk = __builtin_amdgcn_cvt_pk_fp8_f32(wr[c0], wr[c1], 0, false);
    char* w1f = (char*)(wsc + WS_W1F);
    const int off = (h >> 4) * 8192 + (p >> 5) * 512 +
                    (((p >> 3) & 3) * 16 + (h & 15)) * 8 + (p & 7);
    *(ushort*)(w1f + off) = (ushort)pk;
  }
  // bf16 extras step (K-step 16): {w512..w516, b1, 0,0} at k-octant 0
  if (tid == 0) {
    ushort* w1x = (ushort*)(wsc + WS_W1X);
    const int nb = (h >> 4) * 512;
    uint4 g0;
    g0.x = pk2(wr[512], wr[513]);
    g0.y = pk2(wr[514], wr[515]);
    g0.z = pk2(wr[516], b1[h]);
    g0.w = 0u;
    *(uint4*)(w1x + nb + (h & 15) * 8) = g0;
    const uint4 z = {0u, 0u, 0u, 0u};
    *(uint4*)(w1x + nb + (16 + (h & 15)) * 8) = z;
    *(uint4*)(w1x + nb + (32 + (h & 15)) * 8) = z;
    *(uint4*)(w1x + nb + (48 + (h & 15)) * 8) = z;
  }

  if (blockIdx.x == 0) {
    __shared__ float scr[4];
    float lt0 = log_tau2[tid], lt1 = log_tau2[256 + tid];
    float mc0 = mu_c[tid], mc1 = mu_c[256 + tid];
    float it0 = __expf(-lt0), it1 = __expf(-lt1);
    wsc[WS_DIT + tid] = it1 - it0;
    wsc[WS_E + tid] = 2.0f * (mc1 * it1 - mc0 * it0);
    float g = mc1 * mc1 * it1 - mc0 * mc0 * it0 + (lt1 - lt0);
    float sg = block_sum(g, scr);
    if (tid == 0) wsc[WS_C0] = (log_prior[1] - log_prior[0]) - 0.5f * sg;
  }
}

// ---------------------------------------------------------------------------
// Token kernel: 32 tokens/block, 256 threads (4 waves), 8 blocks/CU
// (LDS 18.9 KB, VGPR cap 64 via __launch_bounds__(256,8)).
// Phase 1: stats in regs (DPP row8 reduce); X staged as fp8 e4m3 into
//          XOR-swizzled LDS — ONE uint4 write per iter ([mu8|lv8] blocks
//          contiguous thanks to the K reorder). Extras row bf16 to axl.
// Phase 2: 16 fp8 MFMA K-steps + 1 bf16 extras K-step into the same f32
//          accumulators; per-wave N=32 (2 frags), M=32 (2 frags).
// Epilogue: relu(acc)*W2, DPP row16 reduce, cross-wave via red2.
// ---------------------------------------------------------------------------
__global__ __launch_bounds__(256, 8) void k_token(
    const float* __restrict__ mu, const float* __restrict__ logvar,
    const float* __restrict__ minutes, const float* __restrict__ W2g,
    const float* __restrict__ b2, const float* __restrict__ wsc,
    float* __restrict__ out_s, float* __restrict__ ws_score,
    float* __restrict__ araw_out) {
  __shared__ __align__(16) char A_l[TPB * 512];   // 16KB fp8, XOR-swizzled
  __shared__ __align__(16) ushort axl[TPB * 32];  // 2KB bf16 extras rows
  __shared__ float red2[4][TPB];

  const int tid = threadIdx.x;
  const int w = tid >> 6;
  const int l = tid & 63;
  const int tokbase = blockIdx.x * TPB;
  const float C0 = wsc[WS_C0];

  // zero axl tails (bytes 16..63 of each 64B row)
  if (tid < 96) {
    const int row = tid & 31;
    const int c = tid >> 5;
    const uint4 z = {0u, 0u, 0u, 0u};
    *(uint4*)((char*)axl + row * 64 + 16 + c * 16) = z;
  }

  // ---- phase 1: stream + in-register stats + fp8 X staging ----
  const int trow = tid >> 3;  // this thread's token, 0..31
  const int l8 = tid & 7;     // 8 lanes per token, 8 d per iter
  const int swz = (trow & 7) << 4;  // 16B-granule XOR
  const size_t gbase = (size_t)(tokbase + trow) * 256 + l8 * 8;
  const float* ditg = wsc + WS_DIT + l8 * 8;
  const float* eg = wsc + WS_E + l8 * 8;
  float Ss = 0.f, Sm = 0.f, Sl = 0.f, Sc = 0.f;
#pragma unroll
  for (int t = 0; t < 4; ++t) {
    const float4 m0 = *(const float4*)(mu + gbase + t * 64);
    const float4 m1 = *(const float4*)(mu + gbase + t * 64 + 4);
    const float4 v0 = *(const float4*)(logvar + gbase + t * 64);
    const float4 v1 = *(const float4*)(logvar + gbase + t * 64 + 4);
    const float4 dA = *(const float4*)(ditg + t * 64);
    const float4 dB = *(const float4*)(ditg + t * 64 + 4);
    const float4 eA = *(const float4*)(eg + t * 64);
    const float4 eB = *(const float4*)(eg + t * 64 + 4);
#define CHUNK(m, lv, dt, ee)                                              \
  {                                                                       \
    const float va = __expf(lv.x), vb = __expf(lv.y), vc = __expf(lv.z),  \
                vd = __expf(lv.w);                                        \
    const float na = __expf(-lv.x), nb = __expf(-lv.y),                   \
                nc = __expf(-lv.z), nd = __expf(-lv.w);                   \
    const float qa = m.x * m.x, qb = m.y * m.y, qc = m.z * m.z,           \
                qd = m.w * m.w;                                           \
    Ss += (va + qa) * dt.x - m.x * ee.x + (vb + qb) * dt.y - m.y * ee.y + \
          (vc + qc) * dt.z - m.z * ee.z + (vd + qd) * dt.w - m.w * ee.w;  \
    Sm += qa + qb + qc + qd;                                              \
    Sl += lv.x + lv.y + lv.z + lv.w;                                      \
    Sc += qa * na + qb * nb + qc * nc + qd * nd;                          \
  }
    CHUNK(m0, v0, dA, eA);
    CHUNK(m1, v1, dB, eB);
#undef CHUNK
    uint4 u;
    u.x = pk4f8(m0.x, m0.y, m0.z, m0.w);  // mu bytes 0..3
    u.y = pk4f8(m1.x, m1.y, m1.z, m1.w);  // mu bytes 4..7
    u.z = pk4f8(v0.x, v0.y, v0.z, v0.w);  // lv bytes 0..3
    u.w = pk4f8(v1.x, v1.y, v1.z, v1.w);  // lv bytes 4..7
    const int col = trow * 512 + (t * 8 + l8) * 16;
    *(uint4*)(A_l + (col ^ swz)) = u;
  }
  // reduce across the 8 lanes of this token (valid at l8==0)
  Ss = row8_sum(Ss);
  Sm = row8_sum(Sm);
  Sl = row8_sum(Sl);
  Sc = row8_sum(Sc);
  if (l8 == 0) {
    const float sval = -0.5f * Ss + C0;
    const float mn = minutes[tokbase + trow];
    uint4 ex;
    ex.x = pk2(sval, mn);
    ex.y = pk2(sqrtf(Sm) * (1.0f / 16.0f), Sl * (1.0f / 256.0f));
    ex.z = pk2(Sc * (1.0f / 256.0f), 1.0f);
    ex.w = 0u;
    *(uint4*)((char*)axl + trow * 64) = ex;
    out_s[tokbase + trow] = sval;
    ws_score[tokbase + trow] = Sc;
  }
  __syncthreads();

  // ---- phase 2: 16 fp8 K-steps + 1 bf16 extras step ----
  f32x4 a00 = {0.f, 0.f, 0.f, 0.f};
  f32x4 a01 = {0.f, 0.f, 0.f, 0.f};
  f32x4 a10 = {0.f, 0.f, 0.f, 0.f};
  f32x4 a11 = {0.f, 0.f, 0.f, 0.f};
  const int m_lane = l & 15;
  const int swzA = (m_lane & 7) << 4;
  const int rowA0 = m_lane * 512;
  const int rowA1 = rowA0 + 16 * 512;
  const char* w1f = (const char*)(wsc + WS_W1F);
  const char* bp0 = w1f + (2 * w) * 8192 + l * 8;
  const char* bp1 = bp0 + 8192;
#pragma unroll 4
  for (int ks = 0; ks < 16; ++ks) {
    const int kOff = ks * 32 + (l >> 4) * 8;
    i64 f0 = *(const i64*)(A_l + ((rowA0 + kOff) ^ swzA));
    i64 f1 = *(const i64*)(A_l + ((rowA1 + kOff) ^ swzA));
    i64 bq0 = *(const i64*)(bp0 + ks * 512);
    i64 bq1 = *(const i64*)(bp1 + ks * 512);
    a00 = __builtin_amdgcn_mfma_f32_16x16x32_fp8_fp8(f0, bq0, a00, 0, 0, 0);
    a01 = __builtin_amdgcn_mfma_f32_16x16x32_fp8_fp8(f0, bq1, a01, 0, 0, 0);
    a10 = __builtin_amdgcn_mfma_f32_16x16x32_fp8_fp8(f1, bq0, a10, 0, 0, 0);
    a11 = __builtin_amdgcn_mfma_f32_16x16x32_fp8_fp8(f1, bq1, a11, 0, 0, 0);
  }
  {  // bf16 extras + bias step (K-step 16)
    const int xb = (l >> 4) * 16;
    bf16x8 f0 = *(const bf16x8*)((char*)axl + m_lane * 64 + xb);
    bf16x8 f1 = *(const bf16x8*)((char*)axl + (m_lane + 16) * 64 + xb);
    const ushort* w1x = (const ushort*)(wsc + WS_W1X);
    bf16x8 bq0 = *(const bf16x8*)(w1x + (2 * w) * 512 + l * 8);
    bf16x8 bq1 = *(const bf16x8*)(w1x + (2 * w + 1) * 512 + l * 8);
    a00 = __builtin_amdgcn_mfma_f32_16x16x32_bf16(f0, bq0, a00, 0, 0, 0);
    a01 = __builtin_amdgcn_mfma_f32_16x16x32_bf16(f0, bq1, a01, 0, 0, 0);
    a10 = __builtin_amdgcn_mfma_f32_16x16x32_bf16(f1, bq0, a10, 0, 0, 0);
    a11 = __builtin_amdgcn_mfma_f32_16x16x32_bf16(f1, bq1, a11, 0, 0, 0);
  }

  // ---- epilogue: relu + W2 dot; DPP reduce over 16 h-lanes ----
  const int g = l >> 4;
  const float w2a = W2g[32 * w + m_lane];
  const float w2b = W2g[32 * w + m_lane + 16];
#pragma unroll
  for (int mf = 0; mf < 2; ++mf) {
    const f32x4 aN0 = mf ? a10 : a00;
    const f32x4 aN1 = mf ? a11 : a01;
#pragma unroll
    for (int r = 0; r < 4; ++r) {
      const int t_loc = 16 * mf + 4 * g + r;
      float cs = fmaxf(aN0[r], 0.f) * w2a + fmaxf(aN1[r], 0.f) * w2b;
      cs = row16_sum(cs);
      if (m_lane == 0) red2[w][t_loc] = cs;
    }
  }
  __syncthreads();
  if (tid < TPB) {
    float z = red2[0][tid] + red2[1][tid] + red2[2][tid] + red2[3][tid] +
              b2[0];
    araw_out[tokbase + tid] = 1.0f / (1.0f + __expf(-z));
  }
}

// ---------------------------------------------------------------------------
// Per-batch-row kernel: 256 blocks, 256 threads x 2 tokens; 4 barriers.
// a_io holds a_raw on entry (written by k_token), final a on exit.
// ---------------------------------------------------------------------------
__global__ __launch_bounds__(256) void k_row(
    const float* __restrict__ minutes, const float* __restrict__ s_in,
    const float* __restrict__ score_in, float* a_io,
    const float* __restrict__ alpha_logits,
    const float* __restrict__ attn_lambda_logit,
    const float* __restrict__ decay_rate_log, float* __restrict__ out_total) {
  __shared__ float scrA[4][4];
  __shared__ float scrB[4];
  __shared__ float scrC[4];
  __shared__ float scrD[4][2];
  const int row = blockIdx.x;
  const int tid = threadIdx.x;
  const int w = tid >> 6;
  const int base = row * 512;
  const float sc0 = score_in[base + tid], sc1 = score_in[base + 256 + tid];
  const float sv0 = s_in[base + tid], sv1 = s_in[base + 256 + tid];
  const float ar0 = a_io[base + tid], ar1 = a_io[base + 256 + tid];
  const float mn0 = minutes[base + tid], mn1 = minutes[base + 256 + tid];

  const float vsc = wave_max(fmaxf(sc0, sc1));
  const float vmn = wave_max(fmaxf(mn0, mn1));
  const float var_ = wave_sum(ar0 + ar1);
  if ((tid & 63) == 0) {
    scrA[w][0] = vsc;
    scrA[w][1] = vmn;
    scrA[w][2] = var_;
  }
  __syncthreads();
  const float msc = fmaxf(fmaxf(scrA[0][0], scrA[1][0]),
                          fmaxf(scrA[2][0], scrA[3][0]));
  const float mmn = fmaxf(fmaxf(scrA[0][1], scrA[1][1]),
                          fmaxf(scrA[2][1], scrA[3][1]));
  const float sar = scrA[0][2] + scrA[1][2] + scrA[2][2] + scrA[3][2];

  const float e0 = __expf(sc0 - msc), e1 = __expf(sc1 - msc);
  const float vse = wave_sum(e0 + e1);
  if ((tid & 63) == 0) scrB[w] = vse;
  __syncthreads();
  const float se = scrB[0] + scrB[1] + scrB[2] + scrB[3];

  const float lam = 1.0f / (1.0f + __expf(-attn_lambda_logit[0]));
  const float alpha = 1.0f / (1.0f + __expf(-alpha_logits[0]));
  const float rate = log1pf(__expf(decay_rate_log[0]));

  const float inv_sar = 1.0f / fmaxf(sar, 1e-6f);
  const float inv_se = 1.0f / se;
  const float a00 = lam * ar0 * inv_sar + (1.0f - lam) * e0 * inv_se;
  const float a01 = lam * ar1 * inv_sar + (1.0f - lam) * e1 * inv_se;
  const float dh0 = fmaxf(mmn - mn0, 0.0f) * (1.0f / 60.0f);
  const float dh1 = fmaxf(mmn - mn1, 0.0f) * (1.0f / 60.0f);
  const float w0 = a00 * __expf(-rate * dh0);
  const float w1 = a01 * __expf(-rate * dh1);
  const float vsw = wave_sum(w0 + w1);
  if ((tid & 63) == 0) scrC[w] = vsw;
  __syncthreads();
  const float sw = scrC[0] + scrC[1] + scrC[2] + scrC[3];
  const float inv_sw = 1.0f / fmaxf(sw, 1e-6f);
  const float af0 = w0 * inv_sw, af1 = w1 * inv_sw;
  a_io[base + tid] = af0;
  a_io[base + 256 + tid] = af1;

  const float sg0 = 1.0f / (1.0f + __expf(-sv0));
  const float sg1 = 1.0f / (1.0f + __expf(-sv1));
  const float p0 = fminf(fmaxf(sg0 * af0, 1e-6f), 1.0f - 1e-6f);
  const float p1 = fminf(fmaxf(sg1 * af1, 1e-6f), 1.0f - 1e-6f);
  const float vsm = wave_sum(af0 * sv0 + af1 * sv1);
  const float vlg = wave_sum(log1pf(-p0) + log1pf(-p1));
  if ((tid & 63) == 0) {
    scrD[w][0] = vsm;
    scrD[w][1] = vlg;
  }
  __syncthreads();
  if (tid == 0) {
    const float smain = scrD[0][0] + scrD[1][0] + scrD[2][0] + scrD[3][0];
    const float slg = scrD[0][1] + scrD[1][1] + scrD[2][1] + scrD[3][1];
    float por = 1.0f - __expf(slg);
    por = fminf(fmaxf(por, 1e-6f), 1.0f - 1e-6f);
    const float sor = logf(por) - log1pf(-por);
    out_total[row] = alpha * smain + (1.0f - alpha) * sor;
  }
}

extern "C" void kernel_launch(void* const* d_in, const int* in_sizes, int n_in,
                              void* d_out, int out_size, void* d_ws,
                              size_t ws_size, hipStream_t stream) {
  const float* mu = (const float*)d_in[0];
  const float* logvar = (const float*)d_in[1];
  const float* minutes = (const float*)d_in[2];
  const float* mu_c = (const float*)d_in[3];
  const float* log_tau2 = (const float*)d_in[4];
  const float* log_prior = (const float*)d_in[5];
  const float* W1 = (const float*)d_in[6];
  const float* b1 = (const float*)d_in[7];
  const float* W2 = (const float*)d_in[8];
  const float* b2 = (const float*)d_in[9];
  const float* alpha_logits = (const float*)d_in[10];
  const float* attn_lambda_logit = (const float*)d_in[11];
  const float* decay_rate_log = (const float*)d_in[12];

  float* out = (float*)d_out;
  float* out_total = out;             // [256]
  float* out_s = out + B_DIM;        // [131072]
  float* out_a = out + B_DIM + NTOK; // [131072] — holds a_raw between kernels
  float* wsc = (float*)d_ws;
  float* ws_score = wsc + WS_SCORE;

  k_setup<<<128, 256, 0, stream>>>(W1, b1, mu_c, log_tau2, log_prior, wsc);
  k_token<<<NTOK / TPB, 256, 0, stream>>>(mu, logvar, minutes, W2, b2, wsc,
                                          out_s, ws_score, out_a);
  k_row<<<B_DIM, 256, 0, stream>>>(minutes, out_s, ws_score, out_a,
                                   alpha_logits, attn_lambda_logit,
                                   decay_rate_log, out_total);
}

// Round 11
// 56.767 us; speedup vs baseline: 2.5606x; 1.0273x over previous
//
#include <hip/hip_runtime.h>
#include <hip/hip_bf16.h>

#define B_DIM 256
#define NTOK (256 * 512)
#define W1_LD 517
#define TPB 64  // tokens per k_token block

// workspace float offsets
#define WS_DIT 0
#define WS_E 256             // holds 2*e
#define WS_C0 512
#define WS_W1F 1024          // fp8 frag-ordered [8 nblk][16 ks][64 lane][8B]
                             // = 65536 B = 16384 floats -> [1024, 17408)
#define WS_W1X 17408         // bf16 extras step [8 nblk][64 lane][8]
#define WS_SCORE 20480       // [NTOK]

typedef __attribute__((ext_vector_type(8))) short bf16x8;
typedef __attribute__((ext_vector_type(4))) float f32x4;
typedef long long i64;

__device__ __forceinline__ unsigned pk2(float a, float b) {
  __hip_bfloat162 h = __float22bfloat162_rn(make_float2(a, b));
  unsigned r;
  __builtin_memcpy(&r, &h, 4);
  return r;
}
// pack 4 floats -> 4 fp8 e4m3 bytes in one u32
__device__ __forceinline__ unsigned pk4f8(float a, float b, float c, float d) {
  int r = __builtin_amdgcn_cvt_pk_fp8_f32(a, b, 0, false);
  r = __builtin_amdgcn_cvt_pk_fp8_f32(c, d, r, true);
  return (unsigned)r;
}

// DPP cross-lane add (VALU pipe)
template <int CTRL>
__device__ __forceinline__ float dpp_add(float v) {
  int s = __builtin_amdgcn_update_dpp(0, __float_as_int(v), CTRL, 0xf, 0xf,
                                      true);
  return v + __int_as_float(s);
}
// sum over each group of 8 consecutive lanes (valid at lanes with (l&7)==0).
__device__ __forceinline__ float row8_sum(float v) {
  v = dpp_add<0xB1>(v);   // quad_perm xor1
  v = dpp_add<0x4E>(v);   // quad_perm xor2
  v = dpp_add<0x141>(v);  // row_half_mirror
  return v;
}
// sum over each group of 16 consecutive lanes
__device__ __forceinline__ float row16_sum(float v) {
  v = dpp_add<0xB1>(v);
  v = dpp_add<0x4E>(v);
  v = dpp_add<0x124>(v);  // row_ror:4
  v = dpp_add<0x128>(v);  // row_ror:8
  return v;
}

__device__ __forceinline__ float wave_sum(float v) {
#pragma unroll
  for (int off = 32; off > 0; off >>= 1) v += __shfl_xor(v, off, 64);
  return v;
}
__device__ __forceinline__ float wave_max(float v) {
#pragma unroll
  for (int off = 32; off > 0; off >>= 1) v = fmaxf(v, __shfl_xor(v, off, 64));
  return v;
}
__device__ __forceinline__ float block_sum(float v, float* scr) {
  v = wave_sum(v);
  int wid = threadIdx.x >> 6;
  __syncthreads();
  if ((threadIdx.x & 63) == 0) scr[wid] = v;
  __syncthreads();
  return scr[0] + scr[1] + scr[2] + scr[3];
}

// ---------------------------------------------------------------------------
// K-axis reorder: position p in [0,512) maps to source W1 column
//   (p&15)<8 ? (p>>4)*8 + (p&7) : 256 + (p>>4)*8 + (p&7)
// ---------------------------------------------------------------------------
__global__ __launch_bounds__(256) void k_setup(
    const float* __restrict__ W1, const float* __restrict__ b1,
    const float* __restrict__ mu_c, const float* __restrict__ log_tau2,
    const float* __restrict__ log_prior, float* __restrict__ wsc) {
  const int tid = threadIdx.x;
  const int h = blockIdx.x;
  const float* wr = W1 + h * W1_LD;
  {
    const int p = 2 * tid;
    const int c0 = ((p & 15) < 8) ? (p >> 4) * 8 + (p & 7)
                                  : 256 + (p >> 4) * 8 + (p & 7);
    const int p1 = p + 1;
    const int c1 = ((p1 & 15) < 8) ? (p1 >> 4) * 8 + (p1 & 7)
                                   : 256 + (p1 >> 4) * 8 + (p1 & 7);
    const int pk = __builtin_amdgcn_cvt_pk_fp8_f32(wr[c0], wr[c1], 0, false);
    char* w1f = (char*)(wsc + WS_W1F);
    const int off = (h >> 4) * 8192 + (p >> 5) * 512 +
                    (((p >> 3) & 3) * 16 + (h & 15)) * 8 + (p & 7);
    *(ushort*)(w1f + off) = (ushort)pk;
  }
  if (tid == 0) {
    ushort* w1x = (ushort*)(wsc + WS_W1X);
    const int nb = (h >> 4) * 512;
    uint4 g0;
    g0.x = pk2(wr[512], wr[513]);
    g0.y = pk2(wr[514], wr[515]);
    g0.z = pk2(wr[516], b1[h]);
    g0.w = 0u;
    *(uint4*)(w1x + nb + (h & 15) * 8) = g0;
    const uint4 z = {0u, 0u, 0u, 0u};
    *(uint4*)(w1x + nb + (16 + (h & 15)) * 8) = z;
    *(uint4*)(w1x + nb + (32 + (h & 15)) * 8) = z;
    *(uint4*)(w1x + nb + (48 + (h & 15)) * 8) = z;
  }

  if (blockIdx.x == 0) {
    __shared__ float scr[4];
    float lt0 = log_tau2[tid], lt1 = log_tau2[256 + tid];
    float mc0 = mu_c[tid], mc1 = mu_c[256 + tid];
    float it0 = __expf(-lt0), it1 = __expf(-lt1);
    wsc[WS_DIT + tid] = it1 - it0;
    wsc[WS_E + tid] = 2.0f * (mc1 * it1 - mc0 * it0);
    float g = mc1 * mc1 * it1 - mc0 * mc0 * it0 + (lt1 - lt0);
    float sg = block_sum(g, scr);
    if (tid == 0) wsc[WS_C0] = (log_prior[1] - log_prior[0]) - 0.5f * sg;
  }
}

// ---------------------------------------------------------------------------
// Token kernel: 64 tokens/block, 512 threads (8 waves), 4 blocks/CU
// (LDS 38.9 KB, 32 waves/CU). Wave w owns h in [16w, 16w+16) — B-fragment
// L2 traffic HALVED vs the 32-token tile (each B-frag serves 64 tokens).
// Phase 1: 8 lanes/token; stats in regs (DPP row8); fp8 X staged to
//          XOR-swizzled LDS (one uint4 write/iter). Extras row bf16 to axl.
// Phase 2: 16 fp8 K-steps + 1 bf16 extras step; M=64 (4 frags), N=16.
// ---------------------------------------------------------------------------
__global__ __launch_bounds__(512, 8) void k_token(
    const float* __restrict__ mu, const float* __restrict__ logvar,
    const float* __restrict__ minutes, const float* __restrict__ W2g,
    const float* __restrict__ b2, const float* __restrict__ wsc,
    float* __restrict__ out_s, float* __restrict__ ws_score,
    float* __restrict__ araw_out) {
  __shared__ __align__(16) char A_l[TPB * 512];   // 32KB fp8, XOR-swizzled
  __shared__ __align__(16) ushort axl[TPB * 32];  // 4KB bf16 extras rows
  __shared__ float red2[8][TPB];                  // 2KB

  const int tid = threadIdx.x;
  const int w = tid >> 6;
  const int l = tid & 63;
  const int tokbase = blockIdx.x * TPB;
  const float C0 = wsc[WS_C0];

  // zero axl tails (bytes 16..63 of each 64B row)
  if (tid < 192) {
    const int row = tid & 63;
    const int c = tid >> 6;
    const uint4 z = {0u, 0u, 0u, 0u};
    *(uint4*)((char*)axl + row * 64 + 16 + c * 16) = z;
  }

  // ---- phase 1: stream + in-register stats + fp8 X staging ----
  const int trow = tid >> 3;  // this thread's token, 0..63
  const int l8 = tid & 7;     // 8 lanes per token, 8 d per iter
  const int swz = (trow & 7) << 4;
  const size_t gbase = (size_t)(tokbase + trow) * 256 + l8 * 8;
  const float* ditg = wsc + WS_DIT + l8 * 8;
  const float* eg = wsc + WS_E + l8 * 8;
  float Ss = 0.f, Sm = 0.f, Sl = 0.f, Sc = 0.f;
#pragma unroll
  for (int t = 0; t < 4; ++t) {
    const float4 m0 = *(const float4*)(mu + gbase + t * 64);
    const float4 m1 = *(const float4*)(mu + gbase + t * 64 + 4);
    const float4 v0 = *(const float4*)(logvar + gbase + t * 64);
    const float4 v1 = *(const float4*)(logvar + gbase + t * 64 + 4);
    const float4 dA = *(const float4*)(ditg + t * 64);
    const float4 dB = *(const float4*)(ditg + t * 64 + 4);
    const float4 eA = *(const float4*)(eg + t * 64);
    const float4 eB = *(const float4*)(eg + t * 64 + 4);
#define CHUNK(m, lv, dt, ee)                                              \
  {                                                                       \
    const float va = __expf(lv.x), vb = __expf(lv.y), vc = __expf(lv.z),  \
                vd = __expf(lv.w);                                        \
    const float na = __expf(-lv.x), nb = __expf(-lv.y),                   \
                nc = __expf(-lv.z), nd = __expf(-lv.w);                   \
    const float qa = m.x * m.x, qb = m.y * m.y, qc = m.z * m.z,           \
                qd = m.w * m.w;                                           \
    Ss += (va + qa) * dt.x - m.x * ee.x + (vb + qb) * dt.y - m.y * ee.y + \
          (vc + qc) * dt.z - m.z * ee.z + (vd + qd) * dt.w - m.w * ee.w;  \
    Sm += qa + qb + qc + qd;                                              \
    Sl += lv.x + lv.y + lv.z + lv.w;                                      \
    Sc += qa * na + qb * nb + qc * nc + qd * nd;                          \
  }
    CHUNK(m0, v0, dA, eA);
    CHUNK(m1, v1, dB, eB);
#undef CHUNK
    uint4 u;
    u.x = pk4f8(m0.x, m0.y, m0.z, m0.w);
    u.y = pk4f8(m1.x, m1.y, m1.z, m1.w);
    u.z = pk4f8(v0.x, v0.y, v0.z, v0.w);
    u.w = pk4f8(v1.x, v1.y, v1.z, v1.w);
    const int col = trow * 512 + (t * 8 + l8) * 16;
    *(uint4*)(A_l + (col ^ swz)) = u;
  }
  Ss = row8_sum(Ss);
  Sm = row8_sum(Sm);
  Sl = row8_sum(Sl);
  Sc = row8_sum(Sc);
  if (l8 == 0) {
    const float sval = -0.5f * Ss + C0;
    const float mn = minutes[tokbase + trow];
    uint4 ex;
    ex.x = pk2(sval, mn);
    ex.y = pk2(sqrtf(Sm) * (1.0f / 16.0f), Sl * (1.0f / 256.0f));
    ex.z = pk2(Sc * (1.0f / 256.0f), 1.0f);
    ex.w = 0u;
    *(uint4*)((char*)axl + trow * 64) = ex;
    out_s[tokbase + trow] = sval;
    ws_score[tokbase + trow] = Sc;
  }
  __syncthreads();

  // ---- phase 2: 16 fp8 K-steps + 1 bf16 extras step; M=64, N=16 ----
  f32x4 a0 = {0.f, 0.f, 0.f, 0.f};
  f32x4 a1 = {0.f, 0.f, 0.f, 0.f};
  f32x4 a2 = {0.f, 0.f, 0.f, 0.f};
  f32x4 a3 = {0.f, 0.f, 0.f, 0.f};
  const int m_lane = l & 15;
  const int swzA = (m_lane & 7) << 4;
  const int rowA0 = m_lane * 512;
  const char* w1f = (const char*)(wsc + WS_W1F);
  const char* bp = w1f + w * 8192 + l * 8;
#pragma unroll 4
  for (int ks = 0; ks < 16; ++ks) {
    const int kOff = ks * 32 + (l >> 4) * 8;
    i64 bq = *(const i64*)(bp + ks * 512);
    i64 f0 = *(const i64*)(A_l + ((rowA0 + kOff) ^ swzA));
    i64 f1 = *(const i64*)(A_l + ((rowA0 + 16 * 512 + kOff) ^ swzA));
    i64 f2 = *(const i64*)(A_l + ((rowA0 + 32 * 512 + kOff) ^ swzA));
    i64 f3 = *(const i64*)(A_l + ((rowA0 + 48 * 512 + kOff) ^ swzA));
    a0 = __builtin_amdgcn_mfma_f32_16x16x32_fp8_fp8(f0, bq, a0, 0, 0, 0);
    a1 = __builtin_amdgcn_mfma_f32_16x16x32_fp8_fp8(f1, bq, a1, 0, 0, 0);
    a2 = __builtin_amdgcn_mfma_f32_16x16x32_fp8_fp8(f2, bq, a2, 0, 0, 0);
    a3 = __builtin_amdgcn_mfma_f32_16x16x32_fp8_fp8(f3, bq, a3, 0, 0, 0);
  }
  {  // bf16 extras + bias step (K-step 16)
    const int xb = (l >> 4) * 16;
    const ushort* w1x = (const ushort*)(wsc + WS_W1X);
    bf16x8 bq = *(const bf16x8*)(w1x + w * 512 + l * 8);
    bf16x8 f0 = *(const bf16x8*)((char*)axl + m_lane * 64 + xb);
    bf16x8 f1 = *(const bf16x8*)((char*)axl + (m_lane + 16) * 64 + xb);
    bf16x8 f2 = *(const bf16x8*)((char*)axl + (m_lane + 32) * 64 + xb);
    bf16x8 f3 = *(const bf16x8*)((char*)axl + (m_lane + 48) * 64 + xb);
    a0 = __builtin_amdgcn_mfma_f32_16x16x32_bf16(f0, bq, a0, 0, 0, 0);
    a1 = __builtin_amdgcn_mfma_f32_16x16x32_bf16(f1, bq, a1, 0, 0, 0);
    a2 = __builtin_amdgcn_mfma_f32_16x16x32_bf16(f2, bq, a2, 0, 0, 0);
    a3 = __builtin_amdgcn_mfma_f32_16x16x32_bf16(f3, bq, a3, 0, 0, 0);
  }

  // ---- epilogue: relu + W2 dot; DPP reduce over 16 h-lanes ----
  const int g = l >> 4;
  const float w2a = W2g[16 * w + m_lane];
#pragma unroll
  for (int mf = 0; mf < 4; ++mf) {
    const f32x4 aN = (mf == 0) ? a0 : (mf == 1) ? a1 : (mf == 2) ? a2 : a3;
#pragma unroll
    for (int r = 0; r < 4; ++r) {
      const int t_loc = 16 * mf + 4 * g + r;
      float cs = fmaxf(aN[r], 0.f) * w2a;
      cs = row16_sum(cs);
      if (m_lane == 0) red2[w][t_loc] = cs;
    }
  }
  __syncthreads();
  if (tid < TPB) {
    float z = red2[0][tid] + red2[1][tid] + red2[2][tid] + red2[3][tid] +
              red2[4][tid] + red2[5][tid] + red2[6][tid] + red2[7][tid] +
              b2[0];
    araw_out[tokbase + tid] = 1.0f / (1.0f + __expf(-z));
  }
}

// ---------------------------------------------------------------------------
// Per-batch-row kernel: 256 blocks, 256 threads x 2 tokens; 4 barriers.
// ---------------------------------------------------------------------------
__global__ __launch_bounds__(256) void k_row(
    const float* __restrict__ minutes, const float* __restrict__ s_in,
    const float* __restrict__ score_in, float* a_io,
    const float* __restrict__ alpha_logits,
    const float* __restrict__ attn_lambda_logit,
    const float* __restrict__ decay_rate_log, float* __restrict__ out_total) {
  __shared__ float scrA[4][4];
  __shared__ float scrB[4];
  __shared__ float scrC[4];
  __shared__ float scrD[4][2];
  const int row = blockIdx.x;
  const int tid = threadIdx.x;
  const int w = tid >> 6;
  const int base = row * 512;
  const float sc0 = score_in[base + tid], sc1 = score_in[base + 256 + tid];
  const float sv0 = s_in[base + tid], sv1 = s_in[base + 256 + tid];
  const float ar0 = a_io[base + tid], ar1 = a_io[base + 256 + tid];
  const float mn0 = minutes[base + tid], mn1 = minutes[base + 256 + tid];

  const float vsc = wave_max(fmaxf(sc0, sc1));
  const float vmn = wave_max(fmaxf(mn0, mn1));
  const float var_ = wave_sum(ar0 + ar1);
  if ((tid & 63) == 0) {
    scrA[w][0] = vsc;
    scrA[w][1] = vmn;
    scrA[w][2] = var_;
  }
  __syncthreads();
  const float msc = fmaxf(fmaxf(scrA[0][0], scrA[1][0]),
                          fmaxf(scrA[2][0], scrA[3][0]));
  const float mmn = fmaxf(fmaxf(scrA[0][1], scrA[1][1]),
                          fmaxf(scrA[2][1], scrA[3][1]));
  const float sar = scrA[0][2] + scrA[1][2] + scrA[2][2] + scrA[3][2];

  const float e0 = __expf(sc0 - msc), e1 = __expf(sc1 - msc);
  const float vse = wave_sum(e0 + e1);
  if ((tid & 63) == 0) scrB[w] = vse;
  __syncthreads();
  const float se = scrB[0] + scrB[1] + scrB[2] + scrB[3];

  const float lam = 1.0f / (1.0f + __expf(-attn_lambda_logit[0]));
  const float alpha = 1.0f / (1.0f + __expf(-alpha_logits[0]));
  const float rate = log1pf(__expf(decay_rate_log[0]));

  const float inv_sar = 1.0f / fmaxf(sar, 1e-6f);
  const float inv_se = 1.0f / se;
  const float a00 = lam * ar0 * inv_sar + (1.0f - lam) * e0 * inv_se;
  const float a01 = lam * ar1 * inv_sar + (1.0f - lam) * e1 * inv_se;
  const float dh0 = fmaxf(mmn - mn0, 0.0f) * (1.0f / 60.0f);
  const float dh1 = fmaxf(mmn - mn1, 0.0f) * (1.0f / 60.0f);
  const float w0 = a00 * __expf(-rate * dh0);
  const float w1 = a01 * __expf(-rate * dh1);
  const float vsw = wave_sum(w0 + w1);
  if ((tid & 63) == 0) scrC[w] = vsw;
  __syncthreads();
  const float sw = scrC[0] + scrC[1] + scrC[2] + scrC[3];
  const float inv_sw = 1.0f / fmaxf(sw, 1e-6f);
  const float af0 = w0 * inv_sw, af1 = w1 * inv_sw;
  a_io[base + tid] = af0;
  a_io[base + 256 + tid] = af1;

  const float sg0 = 1.0f / (1.0f + __expf(-sv0));
  const float sg1 = 1.0f / (1.0f + __expf(-sv1));
  const float p0 = fminf(fmaxf(sg0 * af0, 1e-6f), 1.0f - 1e-6f);
  const float p1 = fminf(fmaxf(sg1 * af1, 1e-6f), 1.0f - 1e-6f);
  const float vsm = wave_sum(af0 * sv0 + af1 * sv1);
  const float vlg = wave_sum(log1pf(-p0) + log1pf(-p1));
  if ((tid & 63) == 0) {
    scrD[w][0] = vsm;
    scrD[w][1] = vlg;
  }
  __syncthreads();
  if (tid == 0) {
    const float smain = scrD[0][0] + scrD[1][0] + scrD[2][0] + scrD[3][0];
    const float slg = scrD[0][1] + scrD[1][1] + scrD[2][1] + scrD[3][1];
    float por = 1.0f - __expf(slg);
    por = fminf(fmaxf(por, 1e-6f), 1.0f - 1e-6f);
    const float sor = logf(por) - log1pf(-por);
    out_total[row] = alpha * smain + (1.0f - alpha) * sor;
  }
}

extern "C" void kernel_launch(void* const* d_in, const int* in_sizes, int n_in,
                              void* d_out, int out_size, void* d_ws,
                              size_t ws_size, hipStream_t stream) {
  const float* mu = (const float*)d_in[0];
  const float* logvar = (const float*)d_in[1];
  const float* minutes = (const float*)d_in[2];
  const float* mu_c = (const float*)d_in[3];
  const float* log_tau2 = (const float*)d_in[4];
  const float* log_prior = (const float*)d_in[5];
  const float* W1 = (const float*)d_in[6];
  const float* b1 = (const float*)d_in[7];
  const float* W2 = (const float*)d_in[8];
  const float* b2 = (const float*)d_in[9];
  const float* alpha_logits = (const float*)d_in[10];
  const float* attn_lambda_logit = (const float*)d_in[11];
  const float* decay_rate_log = (const float*)d_in[12];

  float* out = (float*)d_out;
  float* out_total = out;             // [256]
  float* out_s = out + B_DIM;        // [131072]
  float* out_a = out + B_DIM + NTOK; // [131072] — holds a_raw between kernels
  float* wsc = (float*)d_ws;
  float* ws_score = wsc + WS_SCORE;

  k_setup<<<128, 256, 0, stream>>>(W1, b1, mu_c, log_tau2, log_prior, wsc);
  k_token<<<NTOK / TPB, 512, 0, stream>>>(mu, logvar, minutes, W2, b2, wsc,
                                          out_s, ws_score, out_a);
  k_row<<<B_DIM, 256, 0, stream>>>(minutes, out_s, ws_score, out_a,
                                   alpha_logits, attn_lambda_logit,
                                   decay_rate_log, out_total);
}